// Round 1
// baseline (581.153 us; speedup 1.0000x reference)
//
#include <hip/hip_runtime.h>
#include <hip/hip_bf16.h>

#define FEAT 128
#define HID  64
#define OUT  64

// ---------------- CSR build ----------------

__global__ void count_edges(const int* __restrict__ row, int* __restrict__ counts, int E) {
    int e = blockIdx.x * blockDim.x + threadIdx.x;
    if (e < E) atomicAdd(&counts[row[e]], 1);
}

__global__ __launch_bounds__(1024) void scan_block(const int* __restrict__ counts,
                                                   int* __restrict__ incl,
                                                   int* __restrict__ bsums, int N) {
    __shared__ int s[1024];
    int t = threadIdx.x;
    int i = blockIdx.x * 1024 + t;
    s[t] = (i < N) ? counts[i] : 0;
    __syncthreads();
    #pragma unroll
    for (int d = 1; d < 1024; d <<= 1) {
        int x = (t >= d) ? s[t - d] : 0;
        __syncthreads();
        s[t] += x;
        __syncthreads();
    }
    if (i < N) incl[i] = s[t];
    if (t == 1023) bsums[blockIdx.x] = s[t];
}

__global__ __launch_bounds__(128) void scan_bsums(const int* __restrict__ bsums,
                                                  int* __restrict__ bexcl, int NB) {
    __shared__ int s[128];
    int t = threadIdx.x;
    s[t] = (t < NB) ? bsums[t] : 0;
    __syncthreads();
    #pragma unroll
    for (int d = 1; d < 128; d <<= 1) {
        int x = (t >= d) ? s[t - d] : 0;
        __syncthreads();
        s[t] += x;
        __syncthreads();
    }
    if (t < NB) bexcl[t] = (t == 0) ? 0 : s[t - 1];
}

__global__ void finalize_csr(const int* __restrict__ incl, const int* __restrict__ bexcl,
                             int* __restrict__ rowptr, int* __restrict__ cursor, int N) {
    int i = blockIdx.x * blockDim.x + threadIdx.x;
    if (i >= N) return;
    int v = incl[i] + bexcl[i >> 10];
    rowptr[i + 1] = v;
    if (i == 0) rowptr[0] = 0;
    cursor[i] = (i == 0) ? 0 : (incl[i - 1] + bexcl[(i - 1) >> 10]);
}

__global__ void scatter_edges(const int* __restrict__ row, const int* __restrict__ col,
                              const float* __restrict__ vals, int* __restrict__ cursor,
                              int* __restrict__ ecol, float* __restrict__ eval, int E) {
    int e = blockIdx.x * blockDim.x + threadIdx.x;
    if (e >= E) return;
    int r = row[e];
    int p = atomicAdd(&cursor[r], 1);
    ecol[p] = col[e];
    eval[p] = vals[e];
}

// ---------------- GEMM1: h0 = x @ W1 + b1 ----------------

__global__ __launch_bounds__(256) void gemm1(const float* __restrict__ x,
                                             const float* __restrict__ W1,
                                             const float* __restrict__ b1,
                                             float* __restrict__ h0, int N) {
    __shared__ float W1s[FEAT][HID];   // 32 KiB
    __shared__ float b1s[HID];
    int t = threadIdx.x;
    for (int i = t; i < FEAT * HID / 4; i += 256)
        ((float4*)&W1s[0][0])[i] = ((const float4*)W1)[i];
    if (t < HID) b1s[t] = b1[t];
    __syncthreads();

    int wave = t >> 6, lane = t & 63;
    for (int r = blockIdx.x * 4 + wave; r < N; r += gridDim.x * 4) {
        const float4* xr = (const float4*)(x + (size_t)r * FEAT);
        float acc = b1s[lane];
        #pragma unroll
        for (int k4 = 0; k4 < FEAT / 4; ++k4) {
            float4 xv = xr[k4];                 // uniform across lanes -> broadcast
            acc += xv.x * W1s[k4 * 4 + 0][lane];
            acc += xv.y * W1s[k4 * 4 + 1][lane];
            acc += xv.z * W1s[k4 * 4 + 2][lane];
            acc += xv.w * W1s[k4 * 4 + 3][lane];
        }
        h0[(size_t)r * HID + lane] = acc;
    }
}

// ---------------- SpMM helpers ----------------

__device__ inline float gather_accum(const float* __restrict__ feat,
                                     const int* __restrict__ ecol,
                                     const float* __restrict__ eval,
                                     int beg, int end, int lane) {
    float acc = 0.f;
    int e = beg;
    for (; e + 4 <= end; e += 4) {
        int   c0 = ecol[e + 0], c1 = ecol[e + 1], c2 = ecol[e + 2], c3 = ecol[e + 3];
        float v0 = eval[e + 0], v1 = eval[e + 1], v2 = eval[e + 2], v3 = eval[e + 3];
        float g0 = feat[(size_t)c0 * HID + lane];
        float g1 = feat[(size_t)c1 * HID + lane];
        float g2 = feat[(size_t)c2 * HID + lane];
        float g3 = feat[(size_t)c3 * HID + lane];
        acc += v0 * g0; acc += v1 * g1; acc += v2 * g2; acc += v3 * g3;
    }
    for (; e < end; ++e)
        acc += eval[e] * feat[(size_t)ecol[e] * HID + lane];
    return acc;
}

// ---------------- SpMM1 + relu + dropout + GEMM2 fused -> h3 ----------------

__global__ __launch_bounds__(256) void spmm1_fused(const float* __restrict__ h0,
                                                   const int* __restrict__ rowptr,
                                                   const int* __restrict__ ecol,
                                                   const float* __restrict__ eval,
                                                   const float* __restrict__ mask,
                                                   const float* __restrict__ W2,
                                                   const float* __restrict__ b2,
                                                   float* __restrict__ h3, int N) {
    __shared__ float W2s[HID][OUT];    // 16 KiB
    __shared__ float b2s[OUT];
    __shared__ float h2s[4][HID];      // per-wave row staging
    int t = threadIdx.x;
    for (int i = t; i < HID * OUT / 4; i += 256)
        ((float4*)&W2s[0][0])[i] = ((const float4*)W2)[i];
    if (t < OUT) b2s[t] = b2[t];
    __syncthreads();

    int wave = t >> 6, lane = t & 63;
    for (int r = blockIdx.x * 4 + wave; r < N; r += gridDim.x * 4) {
        int beg = rowptr[r], end = rowptr[r + 1];
        float acc = gather_accum(h0, ecol, eval, beg, end, lane);
        float h2 = fmaxf(acc, 0.f) * mask[(size_t)r * HID + lane];
        h2s[wave][lane] = h2;   // wave-synchronous: same-wave write->read, lgkmcnt ordered
        float acc2 = b2s[lane];
        #pragma unroll
        for (int f = 0; f < HID; ++f)
            acc2 += h2s[wave][f] * W2s[f][lane];
        h3[(size_t)r * OUT + lane] = acc2;
    }
}

// ---------------- SpMM2 restricted to idx rows -> out ----------------

__global__ __launch_bounds__(256) void spmm2_idx(const float* __restrict__ h3,
                                                 const int* __restrict__ rowptr,
                                                 const int* __restrict__ ecol,
                                                 const float* __restrict__ eval,
                                                 const int* __restrict__ idx,
                                                 float* __restrict__ out, int NIDX) {
    int t = threadIdx.x;
    int wave = t >> 6, lane = t & 63;
    int i = blockIdx.x * 4 + wave;
    if (i >= NIDX) return;
    int r = idx[i];
    int beg = rowptr[r], end = rowptr[r + 1];
    float acc = gather_accum(h3, ecol, eval, beg, end, lane);
    out[(size_t)i * OUT + lane] = acc;
}

// ---------------- launch ----------------

extern "C" void kernel_launch(void* const* d_in, const int* in_sizes, int n_in,
                              void* d_out, int out_size, void* d_ws, size_t ws_size,
                              hipStream_t stream) {
    const float* x    = (const float*)d_in[0];
    const float* vals = (const float*)d_in[1];
    const float* W1   = (const float*)d_in[2];
    const float* b1   = (const float*)d_in[3];
    const float* W2   = (const float*)d_in[4];
    const float* b2   = (const float*)d_in[5];
    const float* mask = (const float*)d_in[6];
    const int*   row  = (const int*)d_in[7];
    const int*   col  = (const int*)d_in[8];
    const int*   idx  = (const int*)d_in[9];
    float* out = (float*)d_out;

    const int N    = in_sizes[0] / FEAT;
    const int E    = in_sizes[1];
    const int NIDX = in_sizes[9];
    const int NB   = (N + 1023) / 1024;   // scan blocks (98 for N=100000, <=128)

    // workspace layout (256B aligned)
    char* ws = (char*)d_ws;
    size_t off = 0;
    auto alloc = [&](size_t bytes) { void* p = ws + off; off = (off + bytes + 255) & ~(size_t)255; return p; };
    float* h0     = (float*)alloc((size_t)N * HID * 4);
    float* h3     = (float*)alloc((size_t)N * OUT * 4);
    int*   counts = (int*)  alloc((size_t)N * 4);
    int*   incl   = (int*)  alloc((size_t)N * 4);
    int*   rowptr = (int*)  alloc((size_t)(N + 1) * 4);
    int*   cursor = (int*)  alloc((size_t)N * 4);
    int*   bsums  = (int*)  alloc(128 * 4);
    int*   bexcl  = (int*)  alloc(128 * 4);
    int*   ecol   = (int*)  alloc((size_t)E * 4);
    float* eval   = (float*)alloc((size_t)E * 4);
    (void)ws_size;

    hipMemsetAsync(counts, 0, (size_t)N * 4, stream);

    count_edges<<<(E + 255) / 256, 256, 0, stream>>>(row, counts, E);
    scan_block<<<NB, 1024, 0, stream>>>(counts, incl, bsums, N);
    scan_bsums<<<1, 128, 0, stream>>>(bsums, bexcl, NB);
    finalize_csr<<<(N + 255) / 256, 256, 0, stream>>>(incl, bexcl, rowptr, cursor, N);
    scatter_edges<<<(E + 255) / 256, 256, 0, stream>>>(row, col, vals, cursor, ecol, eval, E);

    gemm1<<<2048, 256, 0, stream>>>(x, W1, b1, h0, N);
    spmm1_fused<<<2048, 256, 0, stream>>>(h0, rowptr, ecol, eval, mask, W2, b2, h3, N);
    spmm2_idx<<<(NIDX + 3) / 4, 256, 0, stream>>>(h3, rowptr, ecol, eval, idx, out, NIDX);
}